// Round 12
// baseline (46.472 us; speedup 1.0000x reference)
//
#include <hip/hip_runtime.h>

#define NDIM 128   // feature dim D
#define NOUT 8     // output dim

typedef float     f32x4 __attribute__((ext_vector_type(4)));
typedef _Float16  f16x8 __attribute__((ext_vector_type(8)));

// Kernel 1 (v6, unchanged): per-node projection via MFMA, software-pipelined
// grid-stride loop over 16-node tiles. 512 blocks x 4 waves = 2048 waves.
//   P[n][0..7]  = h[n].Wu[o]          (src half)
//   P[n][8..15] = h[n].Wv[o] + b[o]   (dst half, bias baked in)
__global__ __launch_bounds__(256) void node_proj_kernel(
    const float* __restrict__ h, const float* __restrict__ W,
    const float* __restrict__ b, _Float16* __restrict__ P, int n_nodes) {
  const int lane = threadIdx.x & 63;
  const int wv   = threadIdx.x >> 6;       // wave id in block (0..3)
  const int c    = lane & 15;              // A-row / B-col / D-col
  const int kg   = lane >> 4;              // k-group (0..3)

  // B fragments: W'[col=c][k]; combined row c: c<8 -> Wu[c], c>=8 -> Wv[c-8].
  const float* __restrict__ wp =
      W + (c & 7) * (2 * NDIM) + (c >> 3) * NDIM + kg * 8;
  f16x8 bf[4];
#pragma unroll
  for (int s = 0; s < 4; ++s) {
    const f32x4 w0 = *reinterpret_cast<const f32x4*>(wp + s * 32);
    const f32x4 w1 = *reinterpret_cast<const f32x4*>(wp + s * 32 + 4);
    f16x8 t;
    t[0] = (_Float16)w0.x; t[1] = (_Float16)w0.y;
    t[2] = (_Float16)w0.z; t[3] = (_Float16)w0.w;
    t[4] = (_Float16)w1.x; t[5] = (_Float16)w1.y;
    t[6] = (_Float16)w1.z; t[7] = (_Float16)w1.w;
    bf[s] = t;
  }

  const int ntile   = (n_nodes + 15) >> 4;
  const int wstride = gridDim.x * 4;           // total waves
  const int nmax    = n_nodes - 1;
  const float bias  = (c >= 8) ? b[c - 8] : 0.f;

  auto load_tile = [&](int tile, f32x4 (&a)[8]) {
    const int node = min(tile * 16 + c, nmax);
    const float* __restrict__ hp = h + (size_t)node * NDIM + kg * 8;
#pragma unroll
    for (int s = 0; s < 4; ++s) {
      a[s * 2 + 0] = *reinterpret_cast<const f32x4*>(hp + s * 32);
      a[s * 2 + 1] = *reinterpret_cast<const f32x4*>(hp + s * 32 + 4);
    }
  };
  auto compute_store = [&](int tile, const f32x4 (&a)[8]) {
    f32x4 acc = {0.f, 0.f, 0.f, 0.f};
#pragma unroll
    for (int s = 0; s < 4; ++s) {
      f16x8 af;
#pragma unroll
      for (int j = 0; j < 4; ++j) {
        af[j]     = (_Float16)a[s * 2 + 0][j];
        af[j + 4] = (_Float16)a[s * 2 + 1][j];
      }
      acc = __builtin_amdgcn_mfma_f32_16x16x32_f16(af, bf[s], acc, 0, 0, 0);
    }
    const int rbase = tile * 16 + kg * 4;
#pragma unroll
    for (int i = 0; i < 4; ++i) {
      const int nrow = rbase + i;
      if (nrow < n_nodes)
        P[(size_t)nrow * 16 + c] = (_Float16)(acc[i] + bias);
    }
  };

  int tile = blockIdx.x * 4 + wv;
  if (tile >= ntile) return;

  f32x4 bufA[8], bufB[8];
  load_tile(tile, bufA);
  while (true) {
    const int t1 = tile + wstride;
    if (t1 >= ntile) { compute_store(tile, bufA); break; }
    load_tile(t1, bufB);               // in flight under A's compute
    compute_store(tile, bufA);
    tile = t1;
    const int t2 = tile + wstride;
    if (t2 >= ntile) { compute_store(tile, bufB); break; }
    load_tile(t2, bufA);               // in flight under B's compute
    compute_store(tile, bufB);
    tile = t2;
  }
}

// Kernel 2 (v5): persistent grid-stride edge kernel with a 2-stage index
// pipeline. 1250 blocks x 256 threads x 5 edges/thread == 1.6M exactly.
// Iteration t+1's src/dst index loads are issued BEFORE iteration t's
// gathers stall, hiding the ~600cy HBM index latency under the previous
// iteration's gather+store. P (fp16, 3.2MB) fits per-XCD L2; streaming
// traffic (indices, out) is nontemporal to protect P residency.
__global__ __launch_bounds__(256) void edge_score_kernel(
    const int* __restrict__ src, const int* __restrict__ dst,
    const _Float16* __restrict__ P, float* __restrict__ out, int n_edges) {
  const int stride = gridDim.x * 256;
  int e = blockIdx.x * 256 + threadIdx.x;
  if (e >= n_edges) return;

  const f16x8* __restrict__ Pp = reinterpret_cast<const f16x8*>(P);
  f32x4* __restrict__ op = reinterpret_cast<f32x4*>(out);

  int s_cur = __builtin_nontemporal_load(src + e);
  int d_cur = __builtin_nontemporal_load(dst + e);

  while (true) {
    const int e_next = e + stride;
    int s_nxt = 0, d_nxt = 0;
    const bool more = e_next < n_edges;
    if (more) {
      s_nxt = __builtin_nontemporal_load(src + e_next);   // prefetch next idx
      d_nxt = __builtin_nontemporal_load(dst + e_next);
    }

    const f16x8 sv = Pp[(size_t)s_cur * 2 + 0];   // src half of node
    const f16x8 dv = Pp[(size_t)d_cur * 2 + 1];   // dst half of node
    f32x4 r0, r1;
    r0.x = (float)sv[0] + (float)dv[0]; r0.y = (float)sv[1] + (float)dv[1];
    r0.z = (float)sv[2] + (float)dv[2]; r0.w = (float)sv[3] + (float)dv[3];
    r1.x = (float)sv[4] + (float)dv[4]; r1.y = (float)sv[5] + (float)dv[5];
    r1.z = (float)sv[6] + (float)dv[6]; r1.w = (float)sv[7] + (float)dv[7];
    __builtin_nontemporal_store(r0, op + (size_t)e * 2 + 0);
    __builtin_nontemporal_store(r1, op + (size_t)e * 2 + 1);

    if (!more) break;
    e = e_next;
    s_cur = s_nxt;
    d_cur = d_nxt;
  }
}

// Fallback (only if workspace is too small): direct per-edge computation.
__global__ __launch_bounds__(256) void edge_direct_kernel(
    const float* __restrict__ h, const int* __restrict__ src,
    const int* __restrict__ dst, const float* __restrict__ W,
    const float* __restrict__ b, float* __restrict__ out, int n_edges) {
  const int e = blockIdx.x * 256 + threadIdx.x;
  if (e >= n_edges) return;
  const int s = src[e];
  const int d = dst[e];
  const float4* __restrict__ hs = reinterpret_cast<const float4*>(h + (size_t)s * NDIM);
  const float4* __restrict__ hd = reinterpret_cast<const float4*>(h + (size_t)d * NDIM);
  const float4* __restrict__ W4 = reinterpret_cast<const float4*>(W);

  float acc[NOUT];
#pragma unroll
  for (int o = 0; o < NOUT; ++o) acc[o] = b[o];

  for (int j = 0; j < 32; ++j) {
    const float4 vs = hs[j];
    const float4 vd = hd[j];
#pragma unroll
    for (int o = 0; o < NOUT; ++o) {
      const float4 wu = W4[o * 64 + j];
      const float4 wv = W4[o * 64 + 32 + j];
      acc[o] = fmaf(vs.x, wu.x, fmaf(vs.y, wu.y, fmaf(vs.z, wu.z, fmaf(vs.w, wu.w, acc[o]))));
      acc[o] = fmaf(vd.x, wv.x, fmaf(vd.y, wv.y, fmaf(vd.z, wv.z, fmaf(vd.w, wv.w, acc[o]))));
    }
  }

  float4 r0, r1;
  r0.x = acc[0]; r0.y = acc[1]; r0.z = acc[2]; r0.w = acc[3];
  r1.x = acc[4]; r1.y = acc[5]; r1.z = acc[6]; r1.w = acc[7];
  float4* __restrict__ op = reinterpret_cast<float4*>(out + (size_t)e * NOUT);
  op[0] = r0;
  op[1] = r1;
}

extern "C" void kernel_launch(void* const* d_in, const int* in_sizes, int n_in,
                              void* d_out, int out_size, void* d_ws, size_t ws_size,
                              hipStream_t stream) {
  const float* h   = (const float*)d_in[0];
  const int*   src = (const int*)d_in[1];
  const int*   dst = (const int*)d_in[2];
  const float* W   = (const float*)d_in[3];
  const float* b   = (const float*)d_in[4];
  float* out = (float*)d_out;

  const int n_nodes = in_sizes[0] / NDIM;
  const int n_edges = in_sizes[1];

  const size_t need = (size_t)n_nodes * 16 * sizeof(_Float16);  // 3.2 MB
  if (ws_size >= need) {
    _Float16* P = (_Float16*)d_ws;
    node_proj_kernel<<<512, 256, 0, stream>>>(h, W, b, P, n_nodes);
    // 1250 blocks: 1250*256*5 == 1.6M edges exactly (no ragged tail).
    edge_score_kernel<<<1250, 256, 0, stream>>>(src, dst, P, out, n_edges);
  } else {
    edge_direct_kernel<<<(n_edges + 255) / 256, 256, 0, stream>>>(h, src, dst, W, b, out, n_edges);
  }
}

// Round 13
// 42.607 us; speedup vs baseline: 1.0907x; 1.0907x over previous
//
#include <hip/hip_runtime.h>

#define NDIM 128   // feature dim D
#define NOUT 8     // output dim

typedef float     f32x4 __attribute__((ext_vector_type(4)));
typedef _Float16  f16x4 __attribute__((ext_vector_type(4)));
typedef _Float16  f16x8 __attribute__((ext_vector_type(8)));

// Kernel 1 (v7): per-node projection via MFMA with SWAPPED operands:
// D = W'(16x128) x h^T(128x16) -> D[out][node]. Lane (c=lane&15, kg=lane>>4)
// now holds node c's outputs kg*4..kg*4+3 -> one packed 8B store per lane
// (wave stores a contiguous 512B block) instead of 4 scattered 2B stores.
// Software-pipelined grid-stride loop over 16-node tiles (512 blocks x 4
// waves; ~3 tiles/wave, next tile's 16 dwordx4 loads in flight under the
// current tile's cvt+MFMA+store).
//   P[n][0..7]  = h[n].Wu[o]          (src half)
//   P[n][8..15] = h[n].Wv[o] + b[o]   (dst half, bias baked in)
__global__ __launch_bounds__(256) void node_proj_kernel(
    const float* __restrict__ h, const float* __restrict__ W,
    const float* __restrict__ b, _Float16* __restrict__ P, int n_nodes) {
  const int lane = threadIdx.x & 63;
  const int wv   = threadIdx.x >> 6;       // wave id in block (0..3)
  const int c    = lane & 15;              // A-row (output) / B-col (node)
  const int kg   = lane >> 4;              // k-group (0..3)

  // A fragments: W'[row=c][k]; combined row c: c<8 -> Wu[c], c>=8 -> Wv[c-8].
  const float* __restrict__ wp =
      W + (c & 7) * (2 * NDIM) + (c >> 3) * NDIM + kg * 8;
  f16x8 bf[4];
#pragma unroll
  for (int s = 0; s < 4; ++s) {
    const f32x4 w0 = *reinterpret_cast<const f32x4*>(wp + s * 32);
    const f32x4 w1 = *reinterpret_cast<const f32x4*>(wp + s * 32 + 4);
    f16x8 t;
    t[0] = (_Float16)w0.x; t[1] = (_Float16)w0.y;
    t[2] = (_Float16)w0.z; t[3] = (_Float16)w0.w;
    t[4] = (_Float16)w1.x; t[5] = (_Float16)w1.y;
    t[6] = (_Float16)w1.z; t[7] = (_Float16)w1.w;
    bf[s] = t;
  }

  const int ntile   = (n_nodes + 15) >> 4;
  const int wstride = gridDim.x * 4;           // total waves
  const int nmax    = n_nodes - 1;

  // Per-lane bias for outputs kg*4..kg*4+3 (only dst half, o>=8 i.e. kg>=2).
  f32x4 bias4 = {0.f, 0.f, 0.f, 0.f};
  if (kg >= 2) bias4 = reinterpret_cast<const f32x4*>(b)[kg - 2];

  auto load_tile = [&](int tile, f32x4 (&a)[8]) {
    const int node = min(tile * 16 + c, nmax);   // B-col = node
    const float* __restrict__ hp = h + (size_t)node * NDIM + kg * 8;
#pragma unroll
    for (int s = 0; s < 4; ++s) {
      a[s * 2 + 0] = *reinterpret_cast<const f32x4*>(hp + s * 32);
      a[s * 2 + 1] = *reinterpret_cast<const f32x4*>(hp + s * 32 + 4);
    }
  };
  auto compute_store = [&](int tile, const f32x4 (&a)[8]) {
    f32x4 acc = {0.f, 0.f, 0.f, 0.f};
#pragma unroll
    for (int s = 0; s < 4; ++s) {
      f16x8 af;
#pragma unroll
      for (int j = 0; j < 4; ++j) {
        af[j]     = (_Float16)a[s * 2 + 0][j];
        af[j + 4] = (_Float16)a[s * 2 + 1][j];
      }
      // SWAPPED: A = W' (rows=outputs), B = h^T (cols=nodes) -> D[out][node]
      acc = __builtin_amdgcn_mfma_f32_16x16x32_f16(bf[s], af, acc, 0, 0, 0);
    }
    // Lane holds node nc = tile*16+c, outputs kg*4..kg*4+3 (contiguous!).
    const int nc = tile * 16 + c;
    if (nc < n_nodes) {
      f16x4 r;
#pragma unroll
      for (int i = 0; i < 4; ++i) r[i] = (_Float16)(acc[i] + bias4[i]);
      *reinterpret_cast<f16x4*>(P + (size_t)nc * 16 + kg * 4) = r;
    }
  };

  int tile = blockIdx.x * 4 + wv;
  if (tile >= ntile) return;

  f32x4 bufA[8], bufB[8];
  load_tile(tile, bufA);
  while (true) {
    const int t1 = tile + wstride;
    if (t1 >= ntile) { compute_store(tile, bufA); break; }
    load_tile(t1, bufB);               // in flight under A's compute
    compute_store(tile, bufA);
    tile = t1;
    const int t2 = tile + wstride;
    if (t2 >= ntile) { compute_store(tile, bufB); break; }
    load_tile(t2, bufA);               // in flight under B's compute
    compute_store(tile, bufB);
    tile = t2;
  }
}

// Kernel 2 (v3, reverted from v5 regression): one-shot per-edge gather+add,
// 2 edges/thread. Empirically optimal across R7-R12 (26.3us): the gather
// path is TA/L2-throughput-bound, so more in-flight work only queues.
// P (fp16, 3.2MB) fits per-XCD L2; streaming traffic is nontemporal.
__global__ __launch_bounds__(256) void edge_score_kernel(
    const int* __restrict__ src, const int* __restrict__ dst,
    const _Float16* __restrict__ P, float* __restrict__ out, int n_edges) {
  const int t = threadIdx.x;
  const int e0 = blockIdx.x * 512 + t;
  const int e1 = e0 + 256;
  const bool v0 = e0 < n_edges;
  const bool v1 = e1 < n_edges;

  const f16x8* __restrict__ Pp = reinterpret_cast<const f16x8*>(P);
  f32x4* __restrict__ op = reinterpret_cast<f32x4*>(out);

  int s0 = 0, d0 = 0, s1 = 0, d1 = 0;
  if (v0) {
    s0 = __builtin_nontemporal_load(src + e0);
    d0 = __builtin_nontemporal_load(dst + e0);
  }
  if (v1) {
    s1 = __builtin_nontemporal_load(src + e1);
    d1 = __builtin_nontemporal_load(dst + e1);
  }

  if (v0) {
    const f16x8 sv = Pp[(size_t)s0 * 2 + 0];   // src half of node s0
    const f16x8 dv = Pp[(size_t)d0 * 2 + 1];   // dst half of node d0
    f32x4 r0, r1;
    r0.x = (float)sv[0] + (float)dv[0]; r0.y = (float)sv[1] + (float)dv[1];
    r0.z = (float)sv[2] + (float)dv[2]; r0.w = (float)sv[3] + (float)dv[3];
    r1.x = (float)sv[4] + (float)dv[4]; r1.y = (float)sv[5] + (float)dv[5];
    r1.z = (float)sv[6] + (float)dv[6]; r1.w = (float)sv[7] + (float)dv[7];
    __builtin_nontemporal_store(r0, op + (size_t)e0 * 2 + 0);
    __builtin_nontemporal_store(r1, op + (size_t)e0 * 2 + 1);
  }
  if (v1) {
    const f16x8 sv = Pp[(size_t)s1 * 2 + 0];
    const f16x8 dv = Pp[(size_t)d1 * 2 + 1];
    f32x4 r0, r1;
    r0.x = (float)sv[0] + (float)dv[0]; r0.y = (float)sv[1] + (float)dv[1];
    r0.z = (float)sv[2] + (float)dv[2]; r0.w = (float)sv[3] + (float)dv[3];
    r1.x = (float)sv[4] + (float)dv[4]; r1.y = (float)sv[5] + (float)dv[5];
    r1.z = (float)sv[6] + (float)dv[6]; r1.w = (float)sv[7] + (float)dv[7];
    __builtin_nontemporal_store(r0, op + (size_t)e1 * 2 + 0);
    __builtin_nontemporal_store(r1, op + (size_t)e1 * 2 + 1);
  }
}

// Fallback (only if workspace is too small): direct per-edge computation.
__global__ __launch_bounds__(256) void edge_direct_kernel(
    const float* __restrict__ h, const int* __restrict__ src,
    const int* __restrict__ dst, const float* __restrict__ W,
    const float* __restrict__ b, float* __restrict__ out, int n_edges) {
  const int e = blockIdx.x * 256 + threadIdx.x;
  if (e >= n_edges) return;
  const int s = src[e];
  const int d = dst[e];
  const float4* __restrict__ hs = reinterpret_cast<const float4*>(h + (size_t)s * NDIM);
  const float4* __restrict__ hd = reinterpret_cast<const float4*>(h + (size_t)d * NDIM);
  const float4* __restrict__ W4 = reinterpret_cast<const float4*>(W);

  float acc[NOUT];
#pragma unroll
  for (int o = 0; o < NOUT; ++o) acc[o] = b[o];

  for (int j = 0; j < 32; ++j) {
    const float4 vs = hs[j];
    const float4 vd = hd[j];
#pragma unroll
    for (int o = 0; o < NOUT; ++o) {
      const float4 wu = W4[o * 64 + j];
      const float4 wv = W4[o * 64 + 32 + j];
      acc[o] = fmaf(vs.x, wu.x, fmaf(vs.y, wu.y, fmaf(vs.z, wu.z, fmaf(vs.w, wu.w, acc[o]))));
      acc[o] = fmaf(vd.x, wv.x, fmaf(vd.y, wv.y, fmaf(vd.z, wv.z, fmaf(vd.w, wv.w, acc[o]))));
    }
  }

  float4 r0, r1;
  r0.x = acc[0]; r0.y = acc[1]; r0.z = acc[2]; r0.w = acc[3];
  r1.x = acc[4]; r1.y = acc[5]; r1.z = acc[6]; r1.w = acc[7];
  float4* __restrict__ op = reinterpret_cast<float4*>(out + (size_t)e * NOUT);
  op[0] = r0;
  op[1] = r1;
}

extern "C" void kernel_launch(void* const* d_in, const int* in_sizes, int n_in,
                              void* d_out, int out_size, void* d_ws, size_t ws_size,
                              hipStream_t stream) {
  const float* h   = (const float*)d_in[0];
  const int*   src = (const int*)d_in[1];
  const int*   dst = (const int*)d_in[2];
  const float* W   = (const float*)d_in[3];
  const float* b   = (const float*)d_in[4];
  float* out = (float*)d_out;

  const int n_nodes = in_sizes[0] / NDIM;
  const int n_edges = in_sizes[1];

  const size_t need = (size_t)n_nodes * 16 * sizeof(_Float16);  // 3.2 MB
  if (ws_size >= need) {
    _Float16* P = (_Float16*)d_ws;
    node_proj_kernel<<<512, 256, 0, stream>>>(h, W, b, P, n_nodes);
    edge_score_kernel<<<(n_edges + 511) / 512, 256, 0, stream>>>(src, dst, P, out, n_edges);
  } else {
    edge_direct_kernel<<<(n_edges + 255) / 256, 256, 0, stream>>>(h, src, dst, W, b, out, n_edges);
  }
}